// Round 2
// baseline (76.867 us; speedup 1.0000x reference)
//
#include <hip/hip_runtime.h>
#include <hip/hip_bf16.h>

#define NCAM   16
#define IN     256
#define OUT    128
#define BATCH  8192
#define NSLICE 16
#define SLICE  (BATCH / NSLICE)   // 512
#define XPAD   8
#define XROW   (IN + XPAD)        // 264 shorts per LDS x-row (breaks bank aliasing)

typedef __attribute__((ext_vector_type(8))) short  bfx8;   // 8 bf16 = 4 VGPRs (MFMA A/B frag)
typedef __attribute__((ext_vector_type(4))) short  bfx4;
typedef __attribute__((ext_vector_type(4))) float  fx4;    // MFMA C/D frag

__device__ inline short f2bf(float f) {
    __hip_bfloat16 h = __float2bfloat16(f);   // RNE
    return *reinterpret_cast<short*>(&h);
}

__device__ inline float sigmoidf(float v) {
    return 1.0f / (1.0f + __expf(-v));
}

// Block = (camera c, batch slice): compact matching samples, register-cached W[c]
// bf16 fragments, MFMA 16x16x32 over 16-sample chunks.
__global__ __launch_bounds__(256) void fc_expert_kernel(
    const float* __restrict__ x,     // [BATCH, IN] fp32
    const int*   __restrict__ cam,   // [BATCH]
    const float* __restrict__ W,     // [NCAM, OUT, IN] fp32
    const float* __restrict__ bias,  // [NCAM, OUT] fp32
    float*       __restrict__ out)   // [BATCH, OUT] fp32
{
    __shared__ int   s_list[SLICE];
    __shared__ int   s_m;
    __shared__ short __align__(16) s_x[16 * XROW];   // 16-sample bf16 x tile

    const int slice = blockIdx.x;
    const int c     = blockIdx.y;
    const int tid   = threadIdx.x;
    const int lane  = tid & 63;
    const int w     = tid >> 6;          // wave id 0..3
    const int base  = slice * SLICE;

    const int oq   = lane & 15;          // N-index (output) / M-index (sample) within tile
    const int quad = lane >> 4;          // K sub-block selector

    // ---- wave 0: ballot-compact matching sample indices into s_list ----
    if (tid < 64) {
        int cnt = 0;
        for (int i = 0; i < SLICE; i += 64) {
            int g = base + i + lane;
            bool f = (cam[g] == c);
            unsigned long long mask = __ballot(f);
            int pre = __popcll(mask & ((1ull << lane) - 1ull));
            if (f) s_list[cnt + pre] = g;
            cnt += __popcll(mask);
        }
        if (lane == 0) s_m = cnt;
    }

    // ---- all waves: load W[c] B-fragments into registers (overlaps the scan) ----
    // wave w owns outputs [w*32, w*32+32): two 16-output tiles, full K=256.
    // B frag layout (16x16x32): lane holds B[k][n], n = lane&15, k = quad*8 + j.
    bfx8 bfrag[2][8];
    #pragma unroll
    for (int t = 0; t < 2; ++t) {
        const int o = w * 32 + t * 16 + oq;
        const float* wrow = W + (size_t)(c * OUT + o) * IN + quad * 8;
        #pragma unroll
        for (int kk = 0; kk < 8; ++kk) {
            fx4 f0 = *(const fx4*)(wrow + kk * 32);
            fx4 f1 = *(const fx4*)(wrow + kk * 32 + 4);
            bfx8 s;
            s[0] = f2bf(f0[0]); s[1] = f2bf(f0[1]); s[2] = f2bf(f0[2]); s[3] = f2bf(f0[3]);
            s[4] = f2bf(f1[0]); s[5] = f2bf(f1[1]); s[6] = f2bf(f1[2]); s[7] = f2bf(f1[3]);
            bfrag[t][kk] = s;
        }
    }
    const float b0 = bias[c * OUT + w * 32 + oq];
    const float b1 = bias[c * OUT + w * 32 + 16 + oq];

    __syncthreads();
    const int m = s_m;

    for (int cb = 0; cb < m; cb += 16) {
        // ---- stage up to 16 gathered x rows into LDS as bf16 ----
        // wave w stages rows {w, w+4, w+8, w+12}; lane covers 4 floats of the row.
        #pragma unroll
        for (int rr = 0; rr < 4; ++rr) {
            int row = rr * 4 + w;
            int li  = cb + row;
            bfx4 sv;
            if (li < m) {
                int g = s_list[li];
                fx4 v = *(const fx4*)(x + (size_t)g * IN + lane * 4);
                sv[0] = f2bf(v[0]); sv[1] = f2bf(v[1]); sv[2] = f2bf(v[2]); sv[3] = f2bf(v[3]);
            } else {
                sv[0] = 0; sv[1] = 0; sv[2] = 0; sv[3] = 0;
            }
            *(bfx4*)(s_x + row * XROW + lane * 4) = sv;
        }
        __syncthreads();

        // ---- MFMA: D[s][o] over 16 samples x 32 outputs, K=256 ----
        fx4 acc0 = {0.f, 0.f, 0.f, 0.f};
        fx4 acc1 = {0.f, 0.f, 0.f, 0.f};
        #pragma unroll
        for (int kk = 0; kk < 8; ++kk) {
            bfx8 a = *(const bfx8*)(s_x + oq * XROW + kk * 32 + quad * 8);
            acc0 = __builtin_amdgcn_mfma_f32_16x16x32_bf16(a, bfrag[0][kk], acc0, 0, 0, 0);
            acc1 = __builtin_amdgcn_mfma_f32_16x16x32_bf16(a, bfrag[1][kk], acc1, 0, 0, 0);
        }

        // ---- epilogue: bias + sigmoid + scatter (C/D: col=lane&15, row=quad*4+reg) ----
        #pragma unroll
        for (int r = 0; r < 4; ++r) {
            int srow = quad * 4 + r;
            if (cb + srow < m) {
                int g = s_list[cb + srow];
                float* op = out + (size_t)g * OUT + w * 32 + oq;
                op[0]  = sigmoidf(acc0[r] + b0);
                op[16] = sigmoidf(acc1[r] + b1);
            }
        }
        __syncthreads();   // protect s_x before next chunk's staging
    }
}

extern "C" void kernel_launch(void* const* d_in, const int* in_sizes, int n_in,
                              void* d_out, int out_size, void* d_ws, size_t ws_size,
                              hipStream_t stream) {
    const float* x    = (const float*)d_in[0];
    const int*   cam  = (const int*)d_in[1];
    const float* W    = (const float*)d_in[2];
    const float* bias = (const float*)d_in[3];
    float* out = (float*)d_out;

    dim3 grid(NSLICE, NCAM);
    fc_expert_kernel<<<grid, 256, 0, stream>>>(x, cam, W, bias, out);
}

// Round 3
// 74.008 us; speedup vs baseline: 1.0386x; 1.0386x over previous
//
#include <hip/hip_runtime.h>
#include <hip/hip_bf16.h>

#define NCAM   16
#define IN     256
#define OUT    128
#define BATCH  8192
#define NSLICE 32
#define SLICE  (BATCH / NSLICE)   // 256 samples per slice
#define OHALF  64                 // outputs per block (out-split by 2)
#define XPAD   8
#define XROW   (IN + XPAD)        // 264 shorts per LDS x-row

typedef __attribute__((ext_vector_type(8))) short  bfx8;   // MFMA A/B frag (4 VGPRs)
typedef __attribute__((ext_vector_type(4))) short  bfx4;
typedef __attribute__((ext_vector_type(4))) float  fx4;    // MFMA C/D frag

__device__ inline short f2bf(float f) {
    __hip_bfloat16 h = __float2bfloat16(f);   // RNE
    return *reinterpret_cast<short*>(&h);
}

__device__ inline float sigmoidf(float v) {
    return 1.0f / (1.0f + __expf(-v));
}

// Block = (slice, camera, out-half). 1024 blocks = 4/CU for latency hiding.
// All-wave one-pass ballot compaction; per-wave register-cached W fragments
// (16 outputs x K=256 bf16); MFMA 16x16x32 over 16-sample chunks.
__global__ __launch_bounds__(256, 2) void fc_expert_kernel(
    const float* __restrict__ x,     // [BATCH, IN] fp32
    const int*   __restrict__ cam,   // [BATCH]
    const float* __restrict__ W,     // [NCAM, OUT, IN] fp32
    const float* __restrict__ bias,  // [NCAM, OUT] fp32
    float*       __restrict__ out)   // [BATCH, OUT] fp32
{
    __shared__ int   s_list[SLICE];
    __shared__ int   s_cnt[4];
    __shared__ short __align__(16) s_x[16 * XROW];

    const int slice = blockIdx.x;
    const int c     = blockIdx.y;
    const int obase = blockIdx.z * OHALF;
    const int tid   = threadIdx.x;
    const int lane  = tid & 63;
    const int w     = tid >> 6;          // wave id 0..3
    const int base  = slice * SLICE;

    const int oq   = lane & 15;          // col index within 16-wide MFMA tile
    const int quad = lane >> 4;          // K sub-block / sample-row group

    // ---- issue all global loads up front (overlap VMEM latency with VALU) ----
    const int g0   = base + w * 64 + lane;          // this wave's scan quarter
    const int myc  = cam[g0];

    // wave w owns outputs [obase + w*16, obase + w*16 + 16)
    const int o = obase + w * 16 + oq;
    const float* wrow = W + (size_t)(c * OUT + o) * IN + quad * 8;
    fx4 wt[16];
    #pragma unroll
    for (int kk = 0; kk < 8; ++kk) {
        wt[2 * kk]     = *(const fx4*)(wrow + kk * 32);
        wt[2 * kk + 1] = *(const fx4*)(wrow + kk * 32 + 4);
    }
    const float bo = bias[c * OUT + o];

    // ---- one-pass parallel compaction: each wave ballots its 64 entries ----
    const bool f = (myc == c);
    const unsigned long long mask = __ballot(f);
    if (lane == 0) s_cnt[w] = __popcll(mask);
    __syncthreads();
    int off = 0;
    #pragma unroll
    for (int ww = 0; ww < 4; ++ww) off += (ww < w) ? s_cnt[ww] : 0;
    const int m = s_cnt[0] + s_cnt[1] + s_cnt[2] + s_cnt[3];
    const int pre = __popcll(mask & ((1ull << lane) - 1ull));
    if (f) s_list[off + pre] = g0;

    // ---- convert W fragments to bf16 while the barrier settles ----
    bfx8 bfrag[8];
    #pragma unroll
    for (int kk = 0; kk < 8; ++kk) {
        fx4 f0 = wt[2 * kk], f1 = wt[2 * kk + 1];
        bfx8 s;
        s[0] = f2bf(f0[0]); s[1] = f2bf(f0[1]); s[2] = f2bf(f0[2]); s[3] = f2bf(f0[3]);
        s[4] = f2bf(f1[0]); s[5] = f2bf(f1[1]); s[6] = f2bf(f1[2]); s[7] = f2bf(f1[3]);
        bfrag[kk] = s;
    }
    __syncthreads();

    for (int cb = 0; cb < m; cb += 16) {
        // ---- stage up to 16 gathered x rows into LDS as bf16 ----
        #pragma unroll
        for (int rr = 0; rr < 4; ++rr) {
            int row = rr * 4 + w;
            int li  = cb + row;
            bfx4 sv;
            if (li < m) {
                int g = s_list[li];
                fx4 v = *(const fx4*)(x + (size_t)g * IN + lane * 4);
                sv[0] = f2bf(v[0]); sv[1] = f2bf(v[1]); sv[2] = f2bf(v[2]); sv[3] = f2bf(v[3]);
            } else {
                sv[0] = 0; sv[1] = 0; sv[2] = 0; sv[3] = 0;
            }
            *(bfx4*)(s_x + row * XROW + lane * 4) = sv;
        }
        __syncthreads();

        // ---- MFMA: 16 samples x 16 outputs, K=256 ----
        fx4 acc = {0.f, 0.f, 0.f, 0.f};
        #pragma unroll
        for (int kk = 0; kk < 8; ++kk) {
            bfx8 a = *(const bfx8*)(s_x + oq * XROW + kk * 32 + quad * 8);
            acc = __builtin_amdgcn_mfma_f32_16x16x32_bf16(a, bfrag[kk], acc, 0, 0, 0);
        }

        // ---- epilogue: bias + sigmoid + scatter (C/D: col=lane&15, row=quad*4+r) ----
        #pragma unroll
        for (int r = 0; r < 4; ++r) {
            int srow = quad * 4 + r;
            if (cb + srow < m) {
                int g = s_list[cb + srow];
                out[(size_t)g * OUT + o] = sigmoidf(acc[r] + bo);
            }
        }
        __syncthreads();   // protect s_x before next chunk's staging
    }
}

extern "C" void kernel_launch(void* const* d_in, const int* in_sizes, int n_in,
                              void* d_out, int out_size, void* d_ws, size_t ws_size,
                              hipStream_t stream) {
    const float* x    = (const float*)d_in[0];
    const int*   cam  = (const int*)d_in[1];
    const float* W    = (const float*)d_in[2];
    const float* bias = (const float*)d_in[3];
    float* out = (float*)d_out;

    dim3 grid(NSLICE, NCAM, 2);
    fc_expert_kernel<<<grid, 256, 0, stream>>>(x, cam, W, bias, out);
}